// Round 2
// baseline (2443.524 us; speedup 1.0000x reference)
//
#include <hip/hip_runtime.h>
#include <hip/hip_bf16.h>

#define SEQ 2048
#define HID 4096
#define VOCAB 32000
#define MTOK 4096          // SEQ*BATCH tokens
#define NCHUNK 500         // VOCAB / 64

typedef __attribute__((ext_vector_type(8))) short short8v;
typedef __attribute__((ext_vector_type(4))) float float4v;

__device__ __forceinline__ short f2bf(float x) {
    unsigned u = __float_as_uint(x);
    u += 0x7fff + ((u >> 16) & 1);   // round-to-nearest-even
    return (short)(u >> 16);
}

// Phase 1: tiled bf16 MFMA GEMM (128x128 tile, BK=64) + CE partial epilogue.
// A = hidden [MTOK][HID] f32 (token m = s*2+b), B^T = weight [VOCAB][HID] f32.
// Writes per-(token, 64-col chunk) {max, sum exp(x-max)} partials and the
// label logit.
__global__ __launch_bounds__(256) void gemm_ce_phase1(
    const float* __restrict__ hid, const float* __restrict__ w,
    const int* __restrict__ labels, float2* __restrict__ partials,
    float* __restrict__ labelv)
{
    const int bid = blockIdx.x;
    const int mb = bid & 31;   // m-block fastest: 32 m-blocks share one B panel (L2 reuse)
    const int nb = bid >> 5;   // 0..249
    const int tid = threadIdx.x;
    const int lane = tid & 63;
    const int wid = tid >> 6;          // 4 waves, 2x2
    const int wm = wid >> 1, wn = wid & 1;
    const int l15 = lane & 15;
    const int l4  = lane >> 4;

    // +8 pad: row stride 144B -> 4-bank shift per row -> only 2-way conflict (free)
    __shared__ short As[128][72];
    __shared__ short Bs[128][72];

    float4v acc[4][4];
    #pragma unroll
    for (int i = 0; i < 4; i++)
        #pragma unroll
        for (int j = 0; j < 4; j++) acc[i][j] = (float4v){0.f, 0.f, 0.f, 0.f};

    const int srow = tid >> 3;        // 0..31
    const int scol = (tid & 7) * 8;   // 0..56
    const float* aptr = hid + (size_t)(mb * 128 + srow) * HID + scol;
    const float* bptr = w   + (size_t)(nb * 128 + srow) * HID + scol;

    for (int k0 = 0; k0 < HID; k0 += 64) {
        __syncthreads();
        #pragma unroll
        for (int r = 0; r < 4; r++) {
            const float* ap = aptr + (size_t)r * 32 * HID + k0;
            const float* bp = bptr + (size_t)r * 32 * HID + k0;
            float4 a0 = *(const float4*)ap;
            float4 a1 = *(const float4*)(ap + 4);
            float4 b0 = *(const float4*)bp;
            float4 b1 = *(const float4*)(bp + 4);
            short8v av = { f2bf(a0.x), f2bf(a0.y), f2bf(a0.z), f2bf(a0.w),
                           f2bf(a1.x), f2bf(a1.y), f2bf(a1.z), f2bf(a1.w) };
            short8v bv = { f2bf(b0.x), f2bf(b0.y), f2bf(b0.z), f2bf(b0.w),
                           f2bf(b1.x), f2bf(b1.y), f2bf(b1.z), f2bf(b1.w) };
            *(short8v*)&As[srow + r * 32][scol] = av;
            *(short8v*)&Bs[srow + r * 32][scol] = bv;
        }
        __syncthreads();
        const int kb = l4 * 8;
        #pragma unroll
        for (int kk = 0; kk < 64; kk += 32) {
            short8v a[4], b[4];
            #pragma unroll
            for (int i = 0; i < 4; i++)
                a[i] = *(const short8v*)&As[wm * 64 + i * 16 + l15][kk + kb];
            #pragma unroll
            for (int i = 0; i < 4; i++)
                b[i] = *(const short8v*)&Bs[wn * 64 + i * 16 + l15][kk + kb];
            #pragma unroll
            for (int i = 0; i < 4; i++)
                #pragma unroll
                for (int j = 0; j < 4; j++)
                    acc[i][j] = __builtin_amdgcn_mfma_f32_16x16x32_bf16(
                        a[i], b[j], acc[i][j], 0, 0, 0);
        }
    }

    // Epilogue: per output row (token), reduce max/sumexp over this wave's 64
    // cols (16 lanes x 4 frags), emit one partial per (token, 64-col chunk).
    #pragma unroll
    for (int mi = 0; mi < 4; mi++) {
        #pragma unroll
        for (int j = 0; j < 4; j++) {
            int token = mb * 128 + wm * 64 + mi * 16 + l4 * 4 + j;
            float v0 = acc[mi][0][j], v1 = acc[mi][1][j];
            float v2 = acc[mi][2][j], v3 = acc[mi][3][j];
            float mx = fmaxf(fmaxf(v0, v1), fmaxf(v2, v3));
            #pragma unroll
            for (int d = 1; d < 16; d <<= 1) mx = fmaxf(mx, __shfl_xor(mx, d));
            float sum = expf(v0 - mx) + expf(v1 - mx) + expf(v2 - mx) + expf(v3 - mx);
            #pragma unroll
            for (int d = 1; d < 16; d <<= 1) sum += __shfl_xor(sum, d);
            int chunk = nb * 2 + wn;
            if (l15 == 0)
                partials[(size_t)token * NCHUNK + chunk] = make_float2(mx, sum);
            int lab = labels[(token & 1) * SEQ + (token >> 1)];
            int cbase = nb * 128 + wn * 64 + l15;
            #pragma unroll
            for (int ni = 0; ni < 4; ni++)
                if (cbase + ni * 16 == lab)
                    labelv[token] = (ni == 0 ? v0 : ni == 1 ? v1 : ni == 2 ? v2 : v3);
        }
    }
}

// Phase 2: one wave per token, merge the 500 (max,sum) partials -> nll.
__global__ __launch_bounds__(256) void ce_phase2(
    const float2* __restrict__ partials, const float* __restrict__ labelv,
    float* __restrict__ out)
{
    int token = blockIdx.x * 4 + (threadIdx.x >> 6);
    int lane = threadIdx.x & 63;
    float m = -INFINITY, s = 0.f;
    for (int i = lane; i < NCHUNK; i += 64) {
        float2 p = partials[(size_t)token * NCHUNK + i];
        float nm = fmaxf(m, p.x);
        s = s * expf(m - nm) + p.y * expf(p.x - nm);
        m = nm;
    }
    #pragma unroll
    for (int d = 1; d < 64; d <<= 1) {
        float om = __shfl_xor(m, d);
        float os = __shfl_xor(s, d);
        float nm = fmaxf(m, om);
        s = s * expf(m - nm) + os * expf(om - nm);
        m = nm;
    }
    if (lane == 0) {
        float nll = m + logf(s) - labelv[token];
        out[(token & 1) * SEQ + (token >> 1)] = nll;
    }
}

extern "C" void kernel_launch(void* const* d_in, const int* in_sizes, int n_in,
                              void* d_out, int out_size, void* d_ws, size_t ws_size,
                              hipStream_t stream) {
    const float* hid = (const float*)d_in[0];
    const float* w   = (const float*)d_in[1];
    const int* labels = (const int*)d_in[2];
    float* out = (float*)d_out;

    float2* partials = (float2*)d_ws;                                   // [MTOK][NCHUNK]
    float* labelv = (float*)((char*)d_ws + (size_t)MTOK * NCHUNK * sizeof(float2));

    gemm_ce_phase1<<<dim3(32 * 250), dim3(256), 0, stream>>>(hid, w, labels, partials, labelv);
    ce_phase2<<<dim3(MTOK / 4), dim3(256), 0, stream>>>(partials, labelv, out);
}

// Round 3
// 1819.104 us; speedup vs baseline: 1.3433x; 1.3433x over previous
//
#include <hip/hip_runtime.h>
#include <hip/hip_bf16.h>
#include <stdint.h>

#define SEQ 2048
#define HID 4096
#define VOCAB 32000
#define MTOK 4096          // SEQ*BATCH tokens
#define NCHUNK 500         // VOCAB / 64

typedef __attribute__((ext_vector_type(8))) short short8v;
typedef __attribute__((ext_vector_type(4))) float float4v;

__device__ __forceinline__ short f2bf(float x) {
    unsigned u = __float_as_uint(x);
    u += 0x7fff + ((u >> 16) & 1);   // round-to-nearest-even
    return (short)(u >> 16);
}

// Bulk f32 -> bf16 conversion, 8 elems/thread/iter, grid-stride. BW-bound.
__global__ __launch_bounds__(256) void cvt_f32_bf16(const float* __restrict__ in,
                                                    short* __restrict__ out, int n8) {
    int stride = gridDim.x * 256;
    for (int i = blockIdx.x * 256 + threadIdx.x; i < n8; i += stride) {
        float4 a = *(const float4*)(in + (size_t)i * 8);
        float4 b = *(const float4*)(in + (size_t)i * 8 + 4);
        short8v v = { f2bf(a.x), f2bf(a.y), f2bf(a.z), f2bf(a.w),
                      f2bf(b.x), f2bf(b.y), f2bf(b.z), f2bf(b.w) };
        *(short8v*)(out + (size_t)i * 8) = v;
    }
}

// m97-structure GEMM: 128x128 tile, BK=64, global_load_lds width=16 from
// pre-converted bf16 A[MTOK][HID], B[VOCAB][HID] (both K-contiguous).
// Epilogue: CE (max, sumexp) partials per (token, 64-col chunk) + label logit.
__global__ __launch_bounds__(256) void gemm_ce_bf(
    const short* __restrict__ A, const short* __restrict__ B,
    const int* __restrict__ labels, float2* __restrict__ partials,
    float* __restrict__ labelv)
{
    const int bid = blockIdx.x;
    const int mb = bid & 31;   // m-fastest: 32 m-blocks reuse one B panel via L2/LLC
    const int nb = bid >> 5;   // 0..249
    const int tid = threadIdx.x;
    const int lane = tid & 63;
    const int wid = tid >> 6;          // 4 waves, 2x2
    const int wm = wid >> 1, wn = wid & 1;
    const int l15 = lane & 15;
    const int l4  = lane >> 4;

    // Linear (unpadded) — required by global_load_lds contiguous dest.
    __shared__ short As[128 * 64];
    __shared__ short Bs[128 * 64];

    float4v acc[4][4];
    #pragma unroll
    for (int i = 0; i < 4; i++)
        #pragma unroll
        for (int j = 0; j < 4; j++) acc[i][j] = (float4v){0.f, 0.f, 0.f, 0.f};

    // Staging geometry: thread t covers tile row t>>3 (+32/iter), cols (t&7)*8..+7.
    // LDS byte dest = (iter*256 + t)*16  -> wave-uniform base + lane*16. ✓
    const short* aptr = A + (size_t)(mb * 128 + (tid >> 3)) * HID + (tid & 7) * 8;
    const short* bptr = B + (size_t)(nb * 128 + (tid >> 3)) * HID + (tid & 7) * 8;

    for (int k0 = 0; k0 < HID; k0 += 64) {
        __syncthreads();   // previous tile fully consumed before overwrite
        #pragma unroll
        for (int r = 0; r < 4; r++) {
            __builtin_amdgcn_global_load_lds(
                (const __attribute__((address_space(1))) unsigned int*)(aptr + (size_t)r * 32 * HID + k0),
                (__attribute__((address_space(3))) unsigned int*)(As + ((r * 256 + wid * 64) * 8)),
                16, 0, 0);
            __builtin_amdgcn_global_load_lds(
                (const __attribute__((address_space(1))) unsigned int*)(bptr + (size_t)r * 32 * HID + k0),
                (__attribute__((address_space(3))) unsigned int*)(Bs + ((r * 256 + wid * 64) * 8)),
                16, 0, 0);
        }
        __syncthreads();   // compiler drains vmcnt(0) before s_barrier
        const int kb = l4 * 8;
        #pragma unroll
        for (int kk = 0; kk < 64; kk += 32) {
            short8v a[4], b[4];
            #pragma unroll
            for (int i = 0; i < 4; i++)
                a[i] = *(const short8v*)&As[(wm * 64 + i * 16 + l15) * 64 + kk + kb];
            #pragma unroll
            for (int i = 0; i < 4; i++)
                b[i] = *(const short8v*)&Bs[(wn * 64 + i * 16 + l15) * 64 + kk + kb];
            #pragma unroll
            for (int i = 0; i < 4; i++)
                #pragma unroll
                for (int j = 0; j < 4; j++)
                    acc[i][j] = __builtin_amdgcn_mfma_f32_16x16x32_bf16(
                        a[i], b[j], acc[i][j], 0, 0, 0);
        }
    }

    // Epilogue: per (token, 64-col chunk) -> {max, sum exp(x-max)} + label logit.
    #pragma unroll
    for (int mi = 0; mi < 4; mi++) {
        #pragma unroll
        for (int j = 0; j < 4; j++) {
            int token = mb * 128 + wm * 64 + mi * 16 + l4 * 4 + j;
            float v0 = acc[mi][0][j], v1 = acc[mi][1][j];
            float v2 = acc[mi][2][j], v3 = acc[mi][3][j];
            float mx = fmaxf(fmaxf(v0, v1), fmaxf(v2, v3));
            #pragma unroll
            for (int d = 1; d < 16; d <<= 1) mx = fmaxf(mx, __shfl_xor(mx, d));
            float sum = expf(v0 - mx) + expf(v1 - mx) + expf(v2 - mx) + expf(v3 - mx);
            #pragma unroll
            for (int d = 1; d < 16; d <<= 1) sum += __shfl_xor(sum, d);
            int chunk = nb * 2 + wn;
            if (l15 == 0)
                partials[(size_t)token * NCHUNK + chunk] = make_float2(mx, sum);
            int lab = labels[(token & 1) * SEQ + (token >> 1)];
            int cbase = nb * 128 + wn * 64 + l15;
            #pragma unroll
            for (int ni = 0; ni < 4; ni++)
                if (cbase + ni * 16 == lab)
                    labelv[token] = (ni == 0 ? v0 : ni == 1 ? v1 : ni == 2 ? v2 : v3);
        }
    }
}

// Fallback (round-0 proven path): f32 inputs, reg-staged cvt. Used only if
// ws_size can't hold the bf16 copies.
__global__ __launch_bounds__(256) void gemm_ce_phase1(
    const float* __restrict__ hid, const float* __restrict__ w,
    const int* __restrict__ labels, float2* __restrict__ partials,
    float* __restrict__ labelv)
{
    const int bid = blockIdx.x;
    const int mb = bid & 31;
    const int nb = bid >> 5;
    const int tid = threadIdx.x;
    const int lane = tid & 63;
    const int wid = tid >> 6;
    const int wm = wid >> 1, wn = wid & 1;
    const int l15 = lane & 15;
    const int l4  = lane >> 4;

    __shared__ short As[128][72];
    __shared__ short Bs[128][72];

    float4v acc[4][4];
    #pragma unroll
    for (int i = 0; i < 4; i++)
        #pragma unroll
        for (int j = 0; j < 4; j++) acc[i][j] = (float4v){0.f, 0.f, 0.f, 0.f};

    const int srow = tid >> 3;
    const int scol = (tid & 7) * 8;
    const float* aptr = hid + (size_t)(mb * 128 + srow) * HID + scol;
    const float* bptr = w   + (size_t)(nb * 128 + srow) * HID + scol;

    for (int k0 = 0; k0 < HID; k0 += 64) {
        __syncthreads();
        #pragma unroll
        for (int r = 0; r < 4; r++) {
            const float* ap = aptr + (size_t)r * 32 * HID + k0;
            const float* bp = bptr + (size_t)r * 32 * HID + k0;
            float4 a0 = *(const float4*)ap;
            float4 a1 = *(const float4*)(ap + 4);
            float4 b0 = *(const float4*)bp;
            float4 b1 = *(const float4*)(bp + 4);
            short8v av = { f2bf(a0.x), f2bf(a0.y), f2bf(a0.z), f2bf(a0.w),
                           f2bf(a1.x), f2bf(a1.y), f2bf(a1.z), f2bf(a1.w) };
            short8v bv = { f2bf(b0.x), f2bf(b0.y), f2bf(b0.z), f2bf(b0.w),
                           f2bf(b1.x), f2bf(b1.y), f2bf(b1.z), f2bf(b1.w) };
            *(short8v*)&As[srow + r * 32][scol] = av;
            *(short8v*)&Bs[srow + r * 32][scol] = bv;
        }
        __syncthreads();
        const int kb = l4 * 8;
        #pragma unroll
        for (int kk = 0; kk < 64; kk += 32) {
            short8v a[4], b[4];
            #pragma unroll
            for (int i = 0; i < 4; i++)
                a[i] = *(const short8v*)&As[wm * 64 + i * 16 + l15][kk + kb];
            #pragma unroll
            for (int i = 0; i < 4; i++)
                b[i] = *(const short8v*)&Bs[wn * 64 + i * 16 + l15][kk + kb];
            #pragma unroll
            for (int i = 0; i < 4; i++)
                #pragma unroll
                for (int j = 0; j < 4; j++)
                    acc[i][j] = __builtin_amdgcn_mfma_f32_16x16x32_bf16(
                        a[i], b[j], acc[i][j], 0, 0, 0);
        }
    }

    #pragma unroll
    for (int mi = 0; mi < 4; mi++) {
        #pragma unroll
        for (int j = 0; j < 4; j++) {
            int token = mb * 128 + wm * 64 + mi * 16 + l4 * 4 + j;
            float v0 = acc[mi][0][j], v1 = acc[mi][1][j];
            float v2 = acc[mi][2][j], v3 = acc[mi][3][j];
            float mx = fmaxf(fmaxf(v0, v1), fmaxf(v2, v3));
            #pragma unroll
            for (int d = 1; d < 16; d <<= 1) mx = fmaxf(mx, __shfl_xor(mx, d));
            float sum = expf(v0 - mx) + expf(v1 - mx) + expf(v2 - mx) + expf(v3 - mx);
            #pragma unroll
            for (int d = 1; d < 16; d <<= 1) sum += __shfl_xor(sum, d);
            int chunk = nb * 2 + wn;
            if (l15 == 0)
                partials[(size_t)token * NCHUNK + chunk] = make_float2(mx, sum);
            int lab = labels[(token & 1) * SEQ + (token >> 1)];
            int cbase = nb * 128 + wn * 64 + l15;
            #pragma unroll
            for (int ni = 0; ni < 4; ni++)
                if (cbase + ni * 16 == lab)
                    labelv[token] = (ni == 0 ? v0 : ni == 1 ? v1 : ni == 2 ? v2 : v3);
        }
    }
}

// Phase 2: one wave per token, merge the 500 (max,sum) partials -> nll.
__global__ __launch_bounds__(256) void ce_phase2(
    const float2* __restrict__ partials, const float* __restrict__ labelv,
    float* __restrict__ out)
{
    int token = blockIdx.x * 4 + (threadIdx.x >> 6);
    int lane = threadIdx.x & 63;
    float m = -INFINITY, s = 0.f;
    for (int i = lane; i < NCHUNK; i += 64) {
        float2 p = partials[(size_t)token * NCHUNK + i];
        float nm = fmaxf(m, p.x);
        s = s * expf(m - nm) + p.y * expf(p.x - nm);
        m = nm;
    }
    #pragma unroll
    for (int d = 1; d < 64; d <<= 1) {
        float om = __shfl_xor(m, d);
        float os = __shfl_xor(s, d);
        float nm = fmaxf(m, om);
        s = s * expf(m - nm) + os * expf(om - nm);
        m = nm;
    }
    if (lane == 0) {
        float nll = m + logf(s) - labelv[token];
        out[(token & 1) * SEQ + (token >> 1)] = nll;
    }
}

extern "C" void kernel_launch(void* const* d_in, const int* in_sizes, int n_in,
                              void* d_out, int out_size, void* d_ws, size_t ws_size,
                              hipStream_t stream) {
    const float* hid = (const float*)d_in[0];
    const float* w   = (const float*)d_in[1];
    const int* labels = (const int*)d_in[2];
    float* out = (float*)d_out;

    const size_t WBF  = (size_t)VOCAB * HID * sizeof(short);   // 262,144,000
    const size_t HBF  = (size_t)MTOK * HID * sizeof(short);    //  33,554,432
    const size_t PART = (size_t)MTOK * NCHUNK * sizeof(float2);//  16,384,000
    const size_t LABV = (size_t)MTOK * sizeof(float);

    if (ws_size >= WBF + HBF + PART + LABV) {
        short* wbf = (short*)d_ws;
        short* hbf = (short*)((char*)d_ws + WBF);
        float2* partials = (float2*)((char*)d_ws + WBF + HBF);
        float* labelv = (float*)((char*)d_ws + WBF + HBF + PART);
        cvt_f32_bf16<<<dim3(2048), dim3(256), 0, stream>>>(w, wbf, VOCAB * HID / 8);
        cvt_f32_bf16<<<dim3(2048), dim3(256), 0, stream>>>(hid, hbf, MTOK * HID / 8);
        gemm_ce_bf<<<dim3(32 * 250), dim3(256), 0, stream>>>(hbf, wbf, labels, partials, labelv);
        ce_phase2<<<dim3(MTOK / 4), dim3(256), 0, stream>>>(partials, labelv, out);
    } else {
        float2* partials = (float2*)d_ws;
        float* labelv = (float*)((char*)d_ws + PART);
        gemm_ce_phase1<<<dim3(32 * 250), dim3(256), 0, stream>>>(hid, w, labels, partials, labelv);
        ce_phase2<<<dim3(MTOK / 4), dim3(256), 0, stream>>>(partials, labelv, out);
    }
}

// Round 4
// 1611.270 us; speedup vs baseline: 1.5165x; 1.1290x over previous
//
#include <hip/hip_runtime.h>
#include <hip/hip_bf16.h>
#include <stdint.h>

#define SEQ 2048
#define HID 4096
#define VOCAB 32000
#define MTOK 4096          // SEQ*BATCH tokens
#define NCHUNK 500         // VOCAB / 64

typedef __attribute__((ext_vector_type(8))) short short8v;
typedef __attribute__((ext_vector_type(4))) float float4v;

__device__ __forceinline__ short f2bf(float x) {
    unsigned u = __float_as_uint(x);
    u += 0x7fff + ((u >> 16) & 1);   // round-to-nearest-even
    return (short)(u >> 16);
}

// Bulk f32 -> bf16 conversion, 8 elems/thread/iter, grid-stride. BW-bound.
__global__ __launch_bounds__(256) void cvt_f32_bf16(const float* __restrict__ in,
                                                    short* __restrict__ out, int n8) {
    int stride = gridDim.x * 256;
    for (int i = blockIdx.x * 256 + threadIdx.x; i < n8; i += stride) {
        float4 a = *(const float4*)(in + (size_t)i * 8);
        float4 b = *(const float4*)(in + (size_t)i * 8 + 4);
        short8v v = { f2bf(a.x), f2bf(a.y), f2bf(a.z), f2bf(a.w),
                      f2bf(b.x), f2bf(b.y), f2bf(b.z), f2bf(b.w) };
        *(short8v*)(out + (size_t)i * 8) = v;
    }
}

// m97-structure GEMM + T2 both-sides swizzle: 128x128 tile, BK=64,
// global_load_lds width=16 from bf16 A[MTOK][HID], B[VOCAB][HID].
// LDS dest is linear (required by global_load_lds); swizzle is applied by
// permuting the per-lane GLOBAL source chunk (rule #21 / m173) and XOR-ing
// the same pattern on the ds_read side:
//   LDS[row][chunk] holds global[row][chunk ^ (row&7)]   (16B chunks, 8/row)
__global__ __launch_bounds__(256) void gemm_ce_bf(
    const short* __restrict__ A, const short* __restrict__ B,
    const int* __restrict__ labels, float2* __restrict__ partials,
    float* __restrict__ labelv)
{
    const int bid = blockIdx.x;
    const int mb = bid & 31;   // m-fastest: 32 m-blocks reuse one B panel via L2/LLC
    const int nb = bid >> 5;   // 0..249
    const int tid = threadIdx.x;
    const int lane = tid & 63;
    const int wid = tid >> 6;          // 4 waves, 2x2
    const int wm = wid >> 1, wn = wid & 1;
    const int l15 = lane & 15;
    const int l4  = lane >> 4;

    __shared__ short As[128 * 64];
    __shared__ short Bs[128 * 64];

    float4v acc[4][4];
    #pragma unroll
    for (int i = 0; i < 4; i++)
        #pragma unroll
        for (int j = 0; j < 4; j++) acc[i][j] = (float4v){0.f, 0.f, 0.f, 0.f};

    // Staging: thread t -> LDS slot (r*256 + t), i.e. row = r*32 + (t>>3),
    // chunk = t&7. Source chunk is XOR-swizzled: (t&7) ^ (row&7); row&7 ==
    // (t>>3)&7 for all r (r*32 ≡ 0 mod 8), so it's constant per thread.
    const int srow = tid >> 3;
    const int scol = ((tid & 7) ^ (srow & 7)) * 8;
    const short* aptr = A + (size_t)(mb * 128 + srow) * HID + scol;
    const short* bptr = B + (size_t)(nb * 128 + srow) * HID + scol;

    for (int k0 = 0; k0 < HID; k0 += 64) {
        __syncthreads();   // previous tile fully consumed before overwrite
        #pragma unroll
        for (int r = 0; r < 4; r++) {
            __builtin_amdgcn_global_load_lds(
                (const __attribute__((address_space(1))) unsigned int*)(aptr + (size_t)r * 32 * HID + k0),
                (__attribute__((address_space(3))) unsigned int*)(As + ((r * 256 + wid * 64) * 8)),
                16, 0, 0);
            __builtin_amdgcn_global_load_lds(
                (const __attribute__((address_space(1))) unsigned int*)(bptr + (size_t)r * 32 * HID + k0),
                (__attribute__((address_space(3))) unsigned int*)(Bs + ((r * 256 + wid * 64) * 8)),
                16, 0, 0);
        }
        __syncthreads();
        #pragma unroll
        for (int kk = 0; kk < 64; kk += 32) {
            // Swizzled read: want global chunk (kk/8 + l4) of row; it lives at
            // LDS chunk ((kk/8 + l4) ^ (row&7)), row&7 == l15&7.
            const int cA = (((kk >> 3) + l4) ^ (l15 & 7)) * 8;
            short8v a[4], b[4];
            #pragma unroll
            for (int i = 0; i < 4; i++)
                a[i] = *(const short8v*)&As[(wm * 64 + i * 16 + l15) * 64 + cA];
            #pragma unroll
            for (int i = 0; i < 4; i++)
                b[i] = *(const short8v*)&Bs[(wn * 64 + i * 16 + l15) * 64 + cA];
            #pragma unroll
            for (int i = 0; i < 4; i++)
                #pragma unroll
                for (int j = 0; j < 4; j++)
                    acc[i][j] = __builtin_amdgcn_mfma_f32_16x16x32_bf16(
                        a[i], b[j], acc[i][j], 0, 0, 0);
        }
    }

    // Epilogue: per (token, 64-col chunk) -> {max, sum exp(x-max)} + label logit.
    #pragma unroll
    for (int mi = 0; mi < 4; mi++) {
        #pragma unroll
        for (int j = 0; j < 4; j++) {
            int token = mb * 128 + wm * 64 + mi * 16 + l4 * 4 + j;
            float v0 = acc[mi][0][j], v1 = acc[mi][1][j];
            float v2 = acc[mi][2][j], v3 = acc[mi][3][j];
            float mx = fmaxf(fmaxf(v0, v1), fmaxf(v2, v3));
            #pragma unroll
            for (int d = 1; d < 16; d <<= 1) mx = fmaxf(mx, __shfl_xor(mx, d));
            float sum = expf(v0 - mx) + expf(v1 - mx) + expf(v2 - mx) + expf(v3 - mx);
            #pragma unroll
            for (int d = 1; d < 16; d <<= 1) sum += __shfl_xor(sum, d);
            int chunk = nb * 2 + wn;
            if (l15 == 0)
                partials[(size_t)token * NCHUNK + chunk] = make_float2(mx, sum);
            int lab = labels[(token & 1) * SEQ + (token >> 1)];
            int cbase = nb * 128 + wn * 64 + l15;
            #pragma unroll
            for (int ni = 0; ni < 4; ni++)
                if (cbase + ni * 16 == lab)
                    labelv[token] = (ni == 0 ? v0 : ni == 1 ? v1 : ni == 2 ? v2 : v3);
        }
    }
}

// Fallback (round-0 proven path): f32 inputs, reg-staged cvt. Used only if
// ws_size can't hold the bf16 copies.
__global__ __launch_bounds__(256) void gemm_ce_phase1(
    const float* __restrict__ hid, const float* __restrict__ w,
    const int* __restrict__ labels, float2* __restrict__ partials,
    float* __restrict__ labelv)
{
    const int bid = blockIdx.x;
    const int mb = bid & 31;
    const int nb = bid >> 5;
    const int tid = threadIdx.x;
    const int lane = tid & 63;
    const int wid = tid >> 6;
    const int wm = wid >> 1, wn = wid & 1;
    const int l15 = lane & 15;
    const int l4  = lane >> 4;

    __shared__ short As[128][72];
    __shared__ short Bs[128][72];

    float4v acc[4][4];
    #pragma unroll
    for (int i = 0; i < 4; i++)
        #pragma unroll
        for (int j = 0; j < 4; j++) acc[i][j] = (float4v){0.f, 0.f, 0.f, 0.f};

    const int srow = tid >> 3;
    const int scol = (tid & 7) * 8;
    const float* aptr = hid + (size_t)(mb * 128 + srow) * HID + scol;
    const float* bptr = w   + (size_t)(nb * 128 + srow) * HID + scol;

    for (int k0 = 0; k0 < HID; k0 += 64) {
        __syncthreads();
        #pragma unroll
        for (int r = 0; r < 4; r++) {
            const float* ap = aptr + (size_t)r * 32 * HID + k0;
            const float* bp = bptr + (size_t)r * 32 * HID + k0;
            float4 a0 = *(const float4*)ap;
            float4 a1 = *(const float4*)(ap + 4);
            float4 b0 = *(const float4*)bp;
            float4 b1 = *(const float4*)(bp + 4);
            short8v av = { f2bf(a0.x), f2bf(a0.y), f2bf(a0.z), f2bf(a0.w),
                           f2bf(a1.x), f2bf(a1.y), f2bf(a1.z), f2bf(a1.w) };
            short8v bv = { f2bf(b0.x), f2bf(b0.y), f2bf(b0.z), f2bf(b0.w),
                           f2bf(b1.x), f2bf(b1.y), f2bf(b1.z), f2bf(b1.w) };
            *(short8v*)&As[srow + r * 32][scol] = av;
            *(short8v*)&Bs[srow + r * 32][scol] = bv;
        }
        __syncthreads();
        const int kb = l4 * 8;
        #pragma unroll
        for (int kk = 0; kk < 64; kk += 32) {
            short8v a[4], b[4];
            #pragma unroll
            for (int i = 0; i < 4; i++)
                a[i] = *(const short8v*)&As[wm * 64 + i * 16 + l15][kk + kb];
            #pragma unroll
            for (int i = 0; i < 4; i++)
                b[i] = *(const short8v*)&Bs[wn * 64 + i * 16 + l15][kk + kb];
            #pragma unroll
            for (int i = 0; i < 4; i++)
                #pragma unroll
                for (int j = 0; j < 4; j++)
                    acc[i][j] = __builtin_amdgcn_mfma_f32_16x16x32_bf16(
                        a[i], b[j], acc[i][j], 0, 0, 0);
        }
    }

    #pragma unroll
    for (int mi = 0; mi < 4; mi++) {
        #pragma unroll
        for (int j = 0; j < 4; j++) {
            int token = mb * 128 + wm * 64 + mi * 16 + l4 * 4 + j;
            float v0 = acc[mi][0][j], v1 = acc[mi][1][j];
            float v2 = acc[mi][2][j], v3 = acc[mi][3][j];
            float mx = fmaxf(fmaxf(v0, v1), fmaxf(v2, v3));
            #pragma unroll
            for (int d = 1; d < 16; d <<= 1) mx = fmaxf(mx, __shfl_xor(mx, d));
            float sum = expf(v0 - mx) + expf(v1 - mx) + expf(v2 - mx) + expf(v3 - mx);
            #pragma unroll
            for (int d = 1; d < 16; d <<= 1) sum += __shfl_xor(sum, d);
            int chunk = nb * 2 + wn;
            if (l15 == 0)
                partials[(size_t)token * NCHUNK + chunk] = make_float2(mx, sum);
            int lab = labels[(token & 1) * SEQ + (token >> 1)];
            int cbase = nb * 128 + wn * 64 + l15;
            #pragma unroll
            for (int ni = 0; ni < 4; ni++)
                if (cbase + ni * 16 == lab)
                    labelv[token] = (ni == 0 ? v0 : ni == 1 ? v1 : ni == 2 ? v2 : v3);
        }
    }
}

// Phase 2: one wave per token, merge the 500 (max,sum) partials -> nll.
__global__ __launch_bounds__(256) void ce_phase2(
    const float2* __restrict__ partials, const float* __restrict__ labelv,
    float* __restrict__ out)
{
    int token = blockIdx.x * 4 + (threadIdx.x >> 6);
    int lane = threadIdx.x & 63;
    float m = -INFINITY, s = 0.f;
    for (int i = lane; i < NCHUNK; i += 64) {
        float2 p = partials[(size_t)token * NCHUNK + i];
        float nm = fmaxf(m, p.x);
        s = s * expf(m - nm) + p.y * expf(p.x - nm);
        m = nm;
    }
    #pragma unroll
    for (int d = 1; d < 64; d <<= 1) {
        float om = __shfl_xor(m, d);
        float os = __shfl_xor(s, d);
        float nm = fmaxf(m, om);
        s = s * expf(m - nm) + os * expf(om - nm);
        m = nm;
    }
    if (lane == 0) {
        float nll = m + logf(s) - labelv[token];
        out[(token & 1) * SEQ + (token >> 1)] = nll;
    }
}

extern "C" void kernel_launch(void* const* d_in, const int* in_sizes, int n_in,
                              void* d_out, int out_size, void* d_ws, size_t ws_size,
                              hipStream_t stream) {
    const float* hid = (const float*)d_in[0];
    const float* w   = (const float*)d_in[1];
    const int* labels = (const int*)d_in[2];
    float* out = (float*)d_out;

    const size_t WBF  = (size_t)VOCAB * HID * sizeof(short);   // 262,144,000
    const size_t HBF  = (size_t)MTOK * HID * sizeof(short);    //  33,554,432
    const size_t PART = (size_t)MTOK * NCHUNK * sizeof(float2);//  16,384,000
    const size_t LABV = (size_t)MTOK * sizeof(float);

    if (ws_size >= WBF + HBF + PART + LABV) {
        short* wbf = (short*)d_ws;
        short* hbf = (short*)((char*)d_ws + WBF);
        float2* partials = (float2*)((char*)d_ws + WBF + HBF);
        float* labelv = (float*)((char*)d_ws + WBF + HBF + PART);
        cvt_f32_bf16<<<dim3(2048), dim3(256), 0, stream>>>(w, wbf, VOCAB * HID / 8);
        cvt_f32_bf16<<<dim3(2048), dim3(256), 0, stream>>>(hid, hbf, MTOK * HID / 8);
        gemm_ce_bf<<<dim3(32 * 250), dim3(256), 0, stream>>>(hbf, wbf, labels, partials, labelv);
        ce_phase2<<<dim3(MTOK / 4), dim3(256), 0, stream>>>(partials, labelv, out);
    } else {
        float2* partials = (float2*)d_ws;
        float* labelv = (float*)((char*)d_ws + PART);
        gemm_ce_phase1<<<dim3(32 * 250), dim3(256), 0, stream>>>(hid, w, labels, partials, labelv);
        ce_phase2<<<dim3(MTOK / 4), dim3(256), 0, stream>>>(partials, labelv, out);
    }
}